// Round 1
// baseline (247.469 us; speedup 1.0000x reference)
//
#include <hip/hip_runtime.h>

// PointGatedBlock: SE3 point conv + gated nonlinearity. fp32 in/out.
// R10 = R9 minus the feat LDS staging: B-fragments of GEMM1 are read straight
// from the L2-resident bf16 feat buffer (0.85 MB), lane l15 = row, 16B chunks,
// 2 kk-steps cover an aligned 128B/row segment. LDS drops 66.6KB -> 32.8KB
// (ylds aliased behind Tt inside the phi region) => 4 blocks/CU, 8 waves/SIMD
// (launch_bounds(512,8), VGPR cap 64). Single-barrier fused-phase m-loop kept:
// barrier -> phi(s+1) in regs -> WRITE phi(s+1) to other buffer -> LOAD_DM(s+2)
// -> GEMM1(s) (phi from LDS, feat from global). Pre-kernel converts W+feat to
// bf16 in d_ws. grid 512 = (b, 8-n); block 512; XOR-swizzled phi rows.

typedef __attribute__((ext_vector_type(4))) float f32x4;
typedef __attribute__((ext_vector_type(8))) short s16x8;

#define DI 104
#define DO 144
#define TTST 1688          // Tt row stride (elems)
#define YST 9

#define W_ELEMS 239616     // 16*144*104
#define F_ELEMS 425984     // 4*104*1024

// LDS byte offsets (phi rows: 64 elems = 128 B, XOR-swizzled blocks)
#define OFF_PHI0 0
#define OFF_PHI1 16384                  // 128*64*2
#define OFF_Y 27008                     // behind Tt (8*1688*2) in phi region
#define SMEM_TOTAL 32768                // 32.8KB -> 4 blocks/CU

__device__ __forceinline__ float fexp2(float x) {
#if __has_builtin(__builtin_amdgcn_exp2f)
    return __builtin_amdgcn_exp2f(x);
#else
    return exp2f(x);
#endif
}
__device__ __forceinline__ float flog2(float x) {
#if __has_builtin(__builtin_amdgcn_logf)
    return __builtin_amdgcn_logf(x);
#else
    return log2f(x);
#endif
}
__device__ __forceinline__ float fsqrt_(float x) {
#if __has_builtin(__builtin_amdgcn_sqrtf)
    return __builtin_amdgcn_sqrtf(x);
#else
    return sqrtf(x);
#endif
}
__device__ __forceinline__ float frcp_(float x) {
#if __has_builtin(__builtin_amdgcn_rcpf)
    return __builtin_amdgcn_rcpf(x);
#else
    return 1.0f / x;
#endif
}
__device__ __forceinline__ unsigned int pkbf(float lo, float hi) {
    unsigned int a = __builtin_bit_cast(unsigned int, lo) + 0x8000u;
    unsigned int b = __builtin_bit_cast(unsigned int, hi) + 0x8000u;
    return __builtin_amdgcn_perm(b, a, 0x07060302u);
}
__device__ __forceinline__ unsigned short f2b(float f) {
    return (unsigned short)((__builtin_bit_cast(unsigned int, f) + 0x8000u) >> 16);
}

// ---- pre-kernel: fp32 -> bf16 for W (ws[0..W_ELEMS)) and feat (ws[W_ELEMS..)) ----
__global__ __launch_bounds__(256, 8)
void cvt_kernel(const float* __restrict__ feat_g, const float* __restrict__ W_g,
                unsigned short* __restrict__ ws)
{
    int gid = blockIdx.x * 256 + threadIdx.x;           // 8 elems per thread
    const float* src;
    unsigned short* dst;
    if (gid < W_ELEMS/8) {
        src = W_g + gid*8;  dst = ws + gid*8;
    } else {
        int g2 = gid - W_ELEMS/8;
        src = feat_g + g2*8; dst = ws + W_ELEMS + g2*8;
    }
    f32x4 a = *(const f32x4*)src;
    f32x4 b = *(const f32x4*)(src + 4);
    unsigned int o[4] = { pkbf(a[0],a[1]), pkbf(a[2],a[3]), pkbf(b[0],b[1]), pkbf(b[2],b[3]) };
    *(f32x4*)dst = *(f32x4*)o;
}

// load-tile macro: diff/mask regs for this thread's (n-row, 2 m cols) at m-base M0
#define LOAD_DM(M0)                                                    \
    do {                                                               \
        const float* dp_ = diff_g + (dmrow + (M0) + pml)*3;            \
        dx0 = dp_[0]; dy0 = dp_[1]; dz0 = dp_[2];                      \
        dx1 = dp_[3]; dy1 = dp_[4]; dz1 = dp_[5];                      \
        const float* mp_ = mask_g + dmrow + (M0) + pml;                \
        mk0 = mp_[0]; mk1 = mp_[1];                                    \
    } while (0)

// phi from current dx../mk regs -> pk[0..7] (packed bf16x2 per k-row j)
#define COMPUTE_PHI()                                                  \
    do {                                                               \
        float r0_ = fsqrt_(fmaf(dx0,dx0, fmaf(dy0,dy0, fmaf(dz0,dz0, 1e-12f)))); \
        float r1_ = fsqrt_(fmaf(dx1,dx1, fmaf(dy1,dy1, fmaf(dz1,dz1, 1e-12f)))); \
        float t0_ = r0_ - K0OFF, t1_ = r1_ - K0OFF;                    \
        float E0_ = fmaf(CEXP*t0_, t0_, flog2(mk0));                   \
        float E1_ = fmaf(CEXP*t1_, t1_, flog2(mk1));                   \
        float s0_ = fmaf(A1, r0_, S0B);                                \
        float s1_ = fmaf(A1, r1_, S0B);                                \
        _Pragma("unroll")                                              \
        for (int j_ = 0; j_ < 8; ++j_) {                               \
            pk[j_] = pkbf(fexp2(E0_), fexp2(E1_));                     \
            E0_ += s0_; s0_ += V2;                                     \
            E1_ += s1_; s1_ += V2;                                     \
        }                                                              \
    } while (0)

#define WRITE_PHI(BUF)                                                 \
    do {                                                               \
        unsigned short* pw_ = (BUF) + (pn*16 + kh*8)*64 + pin;         \
        _Pragma("unroll")                                              \
        for (int j_ = 0; j_ < 8; ++j_)                                 \
            *(unsigned int*)(pw_ + j_*64 + ((pblk ^ j_) << 3)) = pk[j_]; \
    } while (0)

// GEMM1: A (phi) from LDS (swizzled), B (feat) from L2-resident global bf16.
// MB = m element base of this tile (s*64). boff[cc] = per-lane feat elem offset
// (b*DI*1024 + i_row*1024 + q*8); kk adds 32 elems, folds into the load imm.
#define GEMM1(PBUF, MB)                                                \
    do {                                                               \
        _Pragma("unroll")                                              \
        for (int kk_ = 0; kk_ < 2; ++kk_) {                            \
            const int mo_ = ((kk_*4 + q) ^ sw) << 3;                   \
            s16x8 a0_ = *(const s16x8*)((PBUF) + ((2*wr    )*16 + l15)*64 + mo_); \
            s16x8 a1_ = *(const s16x8*)((PBUF) + ((2*wr + 1)*16 + l15)*64 + mo_); \
            _Pragma("unroll")                                          \
            for (int cc_ = 0; cc_ < 4; ++cc_) {                        \
                if (ct0 + cc_ < 7) {                                   \
                    s16x8 bf_;                                         \
                    if (ct0 + cc_ == 6) {                              \
                        bf_ = (s16x8){0,0,0,0,0,0,0,0};                \
                        if (l15 < 8)                                   \
                            bf_ = *(const s16x8*)(featbf + boff[cc_] + (MB) + kk_*32); \
                    } else {                                           \
                        bf_ = *(const s16x8*)(featbf + boff[cc_] + (MB) + kk_*32); \
                    }                                                  \
                    acc[0][cc_] = __builtin_amdgcn_mfma_f32_16x16x32_bf16(a0_, bf_, acc[0][cc_], 0, 0, 0); \
                    acc[1][cc_] = __builtin_amdgcn_mfma_f32_16x16x32_bf16(a1_, bf_, acc[1][cc_], 0, 0, 0); \
                }                                                      \
            }                                                          \
        }                                                              \
    } while (0)

__global__ __launch_bounds__(512, 8)
void pgb_kernel(const unsigned short* __restrict__ ws,   // Wbf | featbf
                const float* __restrict__ diff_g,
                const float* __restrict__ mask_g,
                float* __restrict__ out_g)
{
    const unsigned short* Wbf    = ws;
    const unsigned short* featbf = ws + W_ELEMS;

    __shared__ __align__(16) unsigned char smem[SMEM_TOTAL];
    unsigned short* Tt   = (unsigned short*)smem;        // aliases phi bufs (post-barrier)
    float*          ylds = (float*)(smem + OFF_Y);       // behind Tt, still in phi region
    unsigned short* phi0b  = (unsigned short*)(smem + OFF_PHI0);
    unsigned short* phi1b  = (unsigned short*)(smem + OFF_PHI1);

    const int t    = threadIdx.x;
    const int b    = blockIdx.x >> 7;
    const int n0   = (blockIdx.x & 127) << 3;
    const int wave = t >> 6;
    const int lane = t & 63;
    const int l15  = lane & 15;
    const int q    = lane >> 4;
    const int wr   = wave >> 1;          // rowgroup: rowtiles 2wr, 2wr+1 (n_local)
    const int ct0  = (wave & 1) << 2;    // colgroup: coltiles ct0..ct0+3 (skip 7)
    const int sw   = l15 & 7;            // read-side swizzle key (row&7)

    f32x4 acc[2][4];
#pragma unroll
    for (int rr = 0; rr < 2; ++rr)
#pragma unroll
        for (int cc = 0; cc < 4; ++cc)
            acc[rr][cc] = (f32x4){0.f, 0.f, 0.f, 0.f};

    // phi thread mapping: 8 n x 2 k-halves x 32 m-pairs
    const int pn   = t >> 6;             // n-row 0..7 (== wave)
    const int kh   = (t >> 5) & 1;       // k-half: k0 = 8*kh
    const int pml  = (t & 31) << 1;      // m pair (even), 0..62
    const int pblk = (t & 31) >> 2;      // m block 0..7 (write-side swizzle base)
    const int pin  = pml & 7;            // within-block offset
    const float CEXP = -23.083120654223414f;   // -GAMMA * log2(e)
    const float A1   = 6.155498841126244f;     // -2*CEXP*DL
    const float V2   = -0.8207331788168325f;   // 2*CEXP*DL^2
    const float K0OFF = kh ? 1.0666666666666667f : 0.f;
    const float S0B   = kh ? -6.976232019943076f : -0.41036658940841624f;
    const size_t dmrow = (size_t)((b << 10) + n0 + pn) << 10;

    // GEMM1 B-operand global offsets (elems): row i = (ct0+cc)*16 + l15.
    // Lanes of coltile 6 with i >= DI never load (l15<8 guard in GEMM1).
    unsigned int boff[4];
#pragma unroll
    for (int cc = 0; cc < 4; ++cc)
        boff[cc] = (unsigned int)(b * DI * 1024)
                 + (unsigned int)(((ct0 + cc) * 16 + l15) * 1024)
                 + (unsigned int)(q << 3);

    float dx0, dy0, dz0, dx1, dy1, dz1, mk0, mk1;
    unsigned int pk[8];

    // ---- prologue: phi tile 0 -> buf0; then preload tile 1 diff/mask regs ----
    LOAD_DM(0);
    COMPUTE_PHI();
    WRITE_PHI(phi0b);
    LOAD_DM(64);

    // ---- main loop: iter s reads buf(s&1), writes phi tile s+1 -> buf(~s&1) ----
    for (int s = 0; s < 15; ++s) {
        unsigned short* rp = (s & 1) ? phi1b : phi0b;
        unsigned short* wp = (s & 1) ? phi0b : phi1b;
        __syncthreads();
        // phi(s+1) from regs loaded last iter, write into the other buffer.
        COMPUTE_PHI();
        WRITE_PHI(wp);
        // reissue diff/mask loads for tile s+2: consumed next iter after the
        // next barrier -> a full region (GEMM1 + next phi) of latency cover.
        {
            const int mnext = (s < 14 ? (s + 2) : 15) * 64;
            LOAD_DM(mnext);
        }
        // GEMM1 on tile s: phi from LDS, feat direct from L2 bf16 buffer —
        // co-scheduled with the exp2 VALU above; TLP (8 waves/SIMD) hides L2.
        GEMM1(rp, s << 6);
    }
    __syncthreads();
    GEMM1(phi1b, 15 << 6);              // tail: tile 15 lives in buf1

    __syncthreads();   // phi bufs free -> Tt may overwrite

    // ---- acc (C: col=l15=i_local, row=q*4+r=k; tiles (n_local, i-tile)) -> Tt[n][k*104+i]
#pragma unroll
    for (int rr = 0; rr < 2; ++rr) {
        int nloc = 2*wr + rr;
#pragma unroll
        for (int cc = 0; cc < 4; ++cc) {
            int i = (ct0+cc)*16 + l15;
            if (ct0 + cc < 7 && i < DI) {
#pragma unroll
                for (int r = 0; r < 4; ++r)
                    Tt[nloc*TTST + (q*4+r)*DI + i] = f2b(acc[rr][cc][r]);
            }
        }
    }
    __syncthreads();

    // ---- GEMM2: y[o,n] = sum_ki Wbf[k,o,i]*Tt[n][ki]; 52 K-steps of 32 ----
    f32x4 y0 = (f32x4){0.f,0.f,0.f,0.f}, y1 = (f32x4){0.f,0.f,0.f,0.f};
    const int o0 = wave*16 + l15;
    const int o1 = 128 + l15;            // o-tile 8, wave 0's second acc
#pragma unroll 4
    for (int s3 = 0; s3 < 52; ++s3) {
        int a = s3*4 + q;                // 8-elem ki block; k=a/13, i=(a%13)*8
        int k = a / 13;
        int i = (a - k*13) << 3;
        s16x8 bf = *(const s16x8*)(Tt + (l15 & 7)*TTST + s3*32 + q*8);
        s16x8 af = *(const s16x8*)(Wbf + (size_t)(k*DO + o0)*DI + i);
        y0 = __builtin_amdgcn_mfma_f32_16x16x32_bf16(af, bf, y0, 0, 0, 0);
        if (wave == 0) {
            s16x8 ag = *(const s16x8*)(Wbf + (size_t)(k*DO + o1)*DI + i);
            y1 = __builtin_amdgcn_mfma_f32_16x16x32_bf16(ag, bf, y1, 0, 0, 0);
        }
    }
    if (l15 < 8) {
#pragma unroll
        for (int r = 0; r < 4; ++r)
            ylds[(wave*16 + q*4 + r)*YST + l15] = y0[r];
        if (wave == 0) {
#pragma unroll
            for (int r = 0; r < 4; ++r)
                ylds[(128 + q*4 + r)*YST + l15] = y1[r];
        }
    }
    __syncthreads();

    // ---- gating epilogue: out[b, o(<120), n0+nn] fp32 ----
    const float L2E = 1.4426950408889634f;
    for (int idx = t; idx < 120*8; idx += 512) {
        int o = idx >> 3, nn = idx & 7;
        float y = ylds[o*YST + nn];
        float v;
        if (o < 32) {
            v = fmaxf(y, 0.f);
        } else if (o < 80) {
            float g = ylds[(120 + (o-32)/3)*YST + nn];
            v = y * frcp_(1.f + fexp2(-g*L2E));
        } else {
            float g = ylds[(136 + (o-80)/5)*YST + nn];
            v = y * frcp_(1.f + fexp2(-g*L2E));
        }
        out_g[((size_t)(b*120 + o) << 10) + n0 + nn] = v;
    }
}

extern "C" void kernel_launch(void* const* d_in, const int* in_sizes, int n_in,
                              void* d_out, int out_size, void* d_ws, size_t ws_size,
                              hipStream_t stream) {
    const float* feat = (const float*)d_in[0];  // [4,104,1024] fp32
    const float* diff = (const float*)d_in[1];  // [4,1024,1024,3] fp32
    const float* mask = (const float*)d_in[2];  // [4,1024,1024] fp32
    const float* W    = (const float*)d_in[3];  // [16,144,104] fp32
    float* out = (float*)d_out;                 // [4,120,1024] fp32
    unsigned short* ws = (unsigned short*)d_ws; // Wbf (479 KB) + featbf (852 KB)
    (void)in_sizes; (void)n_in; (void)out_size; (void)ws_size;
    cvt_kernel<<<dim3((W_ELEMS + F_ELEMS)/8/256), dim3(256), 0, stream>>>(feat, W, ws);
    pgb_kernel<<<dim3(512), dim3(512), 0, stream>>>(ws, diff, mask, out);
}

// Round 2
// 203.587 us; speedup vs baseline: 1.2155x; 1.2155x over previous
//
#include <hip/hip_runtime.h>

// PointGatedBlock: SE3 point conv + gated nonlinearity. fp32 in/out.
// R11 = R10 with the launch-bounds spill fixed: (512,8) capped VGPR at 64 and
// spilled the main loop (WRITE_SIZE 1.9MB -> 64MB of scratch, 167us). Natural
// footprint is ~80 VGPR, so cap at 6 waves/EU (<=84 VGPR) instead: 3 blocks/CU
// (VGPR-limited; LDS 32.8KB would allow 4) = 24 waves/CU vs R9's 16.
// Structure: B-fragments of GEMM1 read straight from the L2-resident bf16 feat
// buffer (0.85 MB), lane l15 = row, 16B chunks, 2 kk-steps cover an aligned
// 128B/row segment. No feat LDS staging. Single-barrier fused-phase m-loop:
// barrier -> phi(s+1) in regs -> WRITE phi(s+1) to other buffer -> LOAD_DM(s+2)
// -> GEMM1(s) (phi from LDS, feat from global). Pre-kernel converts W+feat to
// bf16 in d_ws. grid 512 = (b, 8-n); block 512; XOR-swizzled phi rows.

typedef __attribute__((ext_vector_type(4))) float f32x4;
typedef __attribute__((ext_vector_type(8))) short s16x8;

#define DI 104
#define DO 144
#define TTST 1688          // Tt row stride (elems)
#define YST 9

#define W_ELEMS 239616     // 16*144*104
#define F_ELEMS 425984     // 4*104*1024

// LDS byte offsets (phi rows: 64 elems = 128 B, XOR-swizzled blocks)
#define OFF_PHI0 0
#define OFF_PHI1 16384                  // 128*64*2
#define OFF_Y 27008                     // behind Tt (8*1688*2) in phi region
#define SMEM_TOTAL 32768                // 32.8KB

__device__ __forceinline__ float fexp2(float x) {
#if __has_builtin(__builtin_amdgcn_exp2f)
    return __builtin_amdgcn_exp2f(x);
#else
    return exp2f(x);
#endif
}
__device__ __forceinline__ float flog2(float x) {
#if __has_builtin(__builtin_amdgcn_logf)
    return __builtin_amdgcn_logf(x);
#else
    return log2f(x);
#endif
}
__device__ __forceinline__ float fsqrt_(float x) {
#if __has_builtin(__builtin_amdgcn_sqrtf)
    return __builtin_amdgcn_sqrtf(x);
#else
    return sqrtf(x);
#endif
}
__device__ __forceinline__ float frcp_(float x) {
#if __has_builtin(__builtin_amdgcn_rcpf)
    return __builtin_amdgcn_rcpf(x);
#else
    return 1.0f / x;
#endif
}
__device__ __forceinline__ unsigned int pkbf(float lo, float hi) {
    unsigned int a = __builtin_bit_cast(unsigned int, lo) + 0x8000u;
    unsigned int b = __builtin_bit_cast(unsigned int, hi) + 0x8000u;
    return __builtin_amdgcn_perm(b, a, 0x07060302u);
}
__device__ __forceinline__ unsigned short f2b(float f) {
    return (unsigned short)((__builtin_bit_cast(unsigned int, f) + 0x8000u) >> 16);
}

// ---- pre-kernel: fp32 -> bf16 for W (ws[0..W_ELEMS)) and feat (ws[W_ELEMS..)) ----
__global__ __launch_bounds__(256, 8)
void cvt_kernel(const float* __restrict__ feat_g, const float* __restrict__ W_g,
                unsigned short* __restrict__ ws)
{
    int gid = blockIdx.x * 256 + threadIdx.x;           // 8 elems per thread
    const float* src;
    unsigned short* dst;
    if (gid < W_ELEMS/8) {
        src = W_g + gid*8;  dst = ws + gid*8;
    } else {
        int g2 = gid - W_ELEMS/8;
        src = feat_g + g2*8; dst = ws + W_ELEMS + g2*8;
    }
    f32x4 a = *(const f32x4*)src;
    f32x4 b = *(const f32x4*)(src + 4);
    unsigned int o[4] = { pkbf(a[0],a[1]), pkbf(a[2],a[3]), pkbf(b[0],b[1]), pkbf(b[2],b[3]) };
    *(f32x4*)dst = *(f32x4*)o;
}

// load-tile macro: diff/mask regs for this thread's (n-row, 2 m cols) at m-base M0
#define LOAD_DM(M0)                                                    \
    do {                                                               \
        const float* dp_ = diff_g + (dmrow + (M0) + pml)*3;            \
        dx0 = dp_[0]; dy0 = dp_[1]; dz0 = dp_[2];                      \
        dx1 = dp_[3]; dy1 = dp_[4]; dz1 = dp_[5];                      \
        const float* mp_ = mask_g + dmrow + (M0) + pml;                \
        mk0 = mp_[0]; mk1 = mp_[1];                                    \
    } while (0)

// phi from current dx../mk regs -> pk[0..7] (packed bf16x2 per k-row j)
#define COMPUTE_PHI()                                                  \
    do {                                                               \
        float r0_ = fsqrt_(fmaf(dx0,dx0, fmaf(dy0,dy0, fmaf(dz0,dz0, 1e-12f)))); \
        float r1_ = fsqrt_(fmaf(dx1,dx1, fmaf(dy1,dy1, fmaf(dz1,dz1, 1e-12f)))); \
        float t0_ = r0_ - K0OFF, t1_ = r1_ - K0OFF;                    \
        float E0_ = fmaf(CEXP*t0_, t0_, flog2(mk0));                   \
        float E1_ = fmaf(CEXP*t1_, t1_, flog2(mk1));                   \
        float s0_ = fmaf(A1, r0_, S0B);                                \
        float s1_ = fmaf(A1, r1_, S0B);                                \
        _Pragma("unroll")                                              \
        for (int j_ = 0; j_ < 8; ++j_) {                               \
            pk[j_] = pkbf(fexp2(E0_), fexp2(E1_));                     \
            E0_ += s0_; s0_ += V2;                                     \
            E1_ += s1_; s1_ += V2;                                     \
        }                                                              \
    } while (0)

#define WRITE_PHI(BUF)                                                 \
    do {                                                               \
        unsigned short* pw_ = (BUF) + (pn*16 + kh*8)*64 + pin;         \
        _Pragma("unroll")                                              \
        for (int j_ = 0; j_ < 8; ++j_)                                 \
            *(unsigned int*)(pw_ + j_*64 + ((pblk ^ j_) << 3)) = pk[j_]; \
    } while (0)

// GEMM1: A (phi) from LDS (swizzled), B (feat) from L2-resident global bf16.
// MB = m element base of this tile (s*64). boff[cc] = per-lane feat elem offset
// (b*DI*1024 + i_row*1024 + q*8); kk adds 32 elems, folds into the load imm.
#define GEMM1(PBUF, MB)                                                \
    do {                                                               \
        _Pragma("unroll")                                              \
        for (int kk_ = 0; kk_ < 2; ++kk_) {                            \
            const int mo_ = ((kk_*4 + q) ^ sw) << 3;                   \
            s16x8 a0_ = *(const s16x8*)((PBUF) + ((2*wr    )*16 + l15)*64 + mo_); \
            s16x8 a1_ = *(const s16x8*)((PBUF) + ((2*wr + 1)*16 + l15)*64 + mo_); \
            _Pragma("unroll")                                          \
            for (int cc_ = 0; cc_ < 4; ++cc_) {                        \
                if (ct0 + cc_ < 7) {                                   \
                    s16x8 bf_;                                         \
                    if (ct0 + cc_ == 6) {                              \
                        bf_ = (s16x8){0,0,0,0,0,0,0,0};                \
                        if (l15 < 8)                                   \
                            bf_ = *(const s16x8*)(featbf + boff[cc_] + (MB) + kk_*32); \
                    } else {                                           \
                        bf_ = *(const s16x8*)(featbf + boff[cc_] + (MB) + kk_*32); \
                    }                                                  \
                    acc[0][cc_] = __builtin_amdgcn_mfma_f32_16x16x32_bf16(a0_, bf_, acc[0][cc_], 0, 0, 0); \
                    acc[1][cc_] = __builtin_amdgcn_mfma_f32_16x16x32_bf16(a1_, bf_, acc[1][cc_], 0, 0, 0); \
                }                                                      \
            }                                                          \
        }                                                              \
    } while (0)

__global__ __launch_bounds__(512, 6)
void pgb_kernel(const unsigned short* __restrict__ ws,   // Wbf | featbf
                const float* __restrict__ diff_g,
                const float* __restrict__ mask_g,
                float* __restrict__ out_g)
{
    const unsigned short* Wbf    = ws;
    const unsigned short* featbf = ws + W_ELEMS;

    __shared__ __align__(16) unsigned char smem[SMEM_TOTAL];
    unsigned short* Tt   = (unsigned short*)smem;        // aliases phi bufs (post-barrier)
    float*          ylds = (float*)(smem + OFF_Y);       // behind Tt, still in phi region
    unsigned short* phi0b  = (unsigned short*)(smem + OFF_PHI0);
    unsigned short* phi1b  = (unsigned short*)(smem + OFF_PHI1);

    const int t    = threadIdx.x;
    const int b    = blockIdx.x >> 7;
    const int n0   = (blockIdx.x & 127) << 3;
    const int wave = t >> 6;
    const int lane = t & 63;
    const int l15  = lane & 15;
    const int q    = lane >> 4;
    const int wr   = wave >> 1;          // rowgroup: rowtiles 2wr, 2wr+1 (n_local)
    const int ct0  = (wave & 1) << 2;    // colgroup: coltiles ct0..ct0+3 (skip 7)
    const int sw   = l15 & 7;            // read-side swizzle key (row&7)

    f32x4 acc[2][4];
#pragma unroll
    for (int rr = 0; rr < 2; ++rr)
#pragma unroll
        for (int cc = 0; cc < 4; ++cc)
            acc[rr][cc] = (f32x4){0.f, 0.f, 0.f, 0.f};

    // phi thread mapping: 8 n x 2 k-halves x 32 m-pairs
    const int pn   = t >> 6;             // n-row 0..7 (== wave)
    const int kh   = (t >> 5) & 1;       // k-half: k0 = 8*kh
    const int pml  = (t & 31) << 1;      // m pair (even), 0..62
    const int pblk = (t & 31) >> 2;      // m block 0..7 (write-side swizzle base)
    const int pin  = pml & 7;            // within-block offset
    const float CEXP = -23.083120654223414f;   // -GAMMA * log2(e)
    const float A1   = 6.155498841126244f;     // -2*CEXP*DL
    const float V2   = -0.8207331788168325f;   // 2*CEXP*DL^2
    const float K0OFF = kh ? 1.0666666666666667f : 0.f;
    const float S0B   = kh ? -6.976232019943076f : -0.41036658940841624f;
    const size_t dmrow = (size_t)((b << 10) + n0 + pn) << 10;

    // GEMM1 B-operand global offsets (elems): row i = (ct0+cc)*16 + l15.
    // Lanes of coltile 6 with i >= DI never load (l15<8 guard in GEMM1).
    unsigned int boff[4];
#pragma unroll
    for (int cc = 0; cc < 4; ++cc)
        boff[cc] = (unsigned int)(b * DI * 1024)
                 + (unsigned int)(((ct0 + cc) * 16 + l15) * 1024)
                 + (unsigned int)(q << 3);

    float dx0, dy0, dz0, dx1, dy1, dz1, mk0, mk1;
    unsigned int pk[8];

    // ---- prologue: phi tile 0 -> buf0; then preload tile 1 diff/mask regs ----
    LOAD_DM(0);
    COMPUTE_PHI();
    WRITE_PHI(phi0b);
    LOAD_DM(64);

    // ---- main loop: iter s reads buf(s&1), writes phi tile s+1 -> buf(~s&1) ----
    for (int s = 0; s < 15; ++s) {
        unsigned short* rp = (s & 1) ? phi1b : phi0b;
        unsigned short* wp = (s & 1) ? phi0b : phi1b;
        __syncthreads();
        // phi(s+1) from regs loaded last iter, write into the other buffer.
        COMPUTE_PHI();
        WRITE_PHI(wp);
        // reissue diff/mask loads for tile s+2: consumed next iter after the
        // next barrier -> a full region (GEMM1 + next phi) of latency cover.
        {
            const int mnext = (s < 14 ? (s + 2) : 15) * 64;
            LOAD_DM(mnext);
        }
        // GEMM1 on tile s: phi from LDS, feat direct from L2 bf16 buffer —
        // co-scheduled with the exp2 VALU above; TLP (6 waves/SIMD) hides L2.
        GEMM1(rp, s << 6);
    }
    __syncthreads();
    GEMM1(phi1b, 15 << 6);              // tail: tile 15 lives in buf1

    __syncthreads();   // phi bufs free -> Tt may overwrite

    // ---- acc (C: col=l15=i_local, row=q*4+r=k; tiles (n_local, i-tile)) -> Tt[n][k*104+i]
#pragma unroll
    for (int rr = 0; rr < 2; ++rr) {
        int nloc = 2*wr + rr;
#pragma unroll
        for (int cc = 0; cc < 4; ++cc) {
            int i = (ct0+cc)*16 + l15;
            if (ct0 + cc < 7 && i < DI) {
#pragma unroll
                for (int r = 0; r < 4; ++r)
                    Tt[nloc*TTST + (q*4+r)*DI + i] = f2b(acc[rr][cc][r]);
            }
        }
    }
    __syncthreads();

    // ---- GEMM2: y[o,n] = sum_ki Wbf[k,o,i]*Tt[n][ki]; 52 K-steps of 32 ----
    f32x4 y0 = (f32x4){0.f,0.f,0.f,0.f}, y1 = (f32x4){0.f,0.f,0.f,0.f};
    const int o0 = wave*16 + l15;
    const int o1 = 128 + l15;            // o-tile 8, wave 0's second acc
#pragma unroll 4
    for (int s3 = 0; s3 < 52; ++s3) {
        int a = s3*4 + q;                // 8-elem ki block; k=a/13, i=(a%13)*8
        int k = a / 13;
        int i = (a - k*13) << 3;
        s16x8 bf = *(const s16x8*)(Tt + (l15 & 7)*TTST + s3*32 + q*8);
        s16x8 af = *(const s16x8*)(Wbf + (size_t)(k*DO + o0)*DI + i);
        y0 = __builtin_amdgcn_mfma_f32_16x16x32_bf16(af, bf, y0, 0, 0, 0);
        if (wave == 0) {
            s16x8 ag = *(const s16x8*)(Wbf + (size_t)(k*DO + o1)*DI + i);
            y1 = __builtin_amdgcn_mfma_f32_16x16x32_bf16(ag, bf, y1, 0, 0, 0);
        }
    }
    if (l15 < 8) {
#pragma unroll
        for (int r = 0; r < 4; ++r)
            ylds[(wave*16 + q*4 + r)*YST + l15] = y0[r];
        if (wave == 0) {
#pragma unroll
            for (int r = 0; r < 4; ++r)
                ylds[(128 + q*4 + r)*YST + l15] = y1[r];
        }
    }
    __syncthreads();

    // ---- gating epilogue: out[b, o(<120), n0+nn] fp32 ----
    const float L2E = 1.4426950408889634f;
    for (int idx = t; idx < 120*8; idx += 512) {
        int o = idx >> 3, nn = idx & 7;
        float y = ylds[o*YST + nn];
        float v;
        if (o < 32) {
            v = fmaxf(y, 0.f);
        } else if (o < 80) {
            float g = ylds[(120 + (o-32)/3)*YST + nn];
            v = y * frcp_(1.f + fexp2(-g*L2E));
        } else {
            float g = ylds[(136 + (o-80)/5)*YST + nn];
            v = y * frcp_(1.f + fexp2(-g*L2E));
        }
        out_g[((size_t)(b*120 + o) << 10) + n0 + nn] = v;
    }
}

extern "C" void kernel_launch(void* const* d_in, const int* in_sizes, int n_in,
                              void* d_out, int out_size, void* d_ws, size_t ws_size,
                              hipStream_t stream) {
    const float* feat = (const float*)d_in[0];  // [4,104,1024] fp32
    const float* diff = (const float*)d_in[1];  // [4,1024,1024,3] fp32
    const float* mask = (const float*)d_in[2];  // [4,1024,1024] fp32
    const float* W    = (const float*)d_in[3];  // [16,144,104] fp32
    float* out = (float*)d_out;                 // [4,120,1024] fp32
    unsigned short* ws = (unsigned short*)d_ws; // Wbf (479 KB) + featbf (852 KB)
    (void)in_sizes; (void)n_in; (void)out_size; (void)ws_size;
    cvt_kernel<<<dim3((W_ELEMS + F_ELEMS)/8/256), dim3(256), 0, stream>>>(feat, W, ws);
    pgb_kernel<<<dim3(512), dim3(512), 0, stream>>>(ws, diff, mask, out);
}

// Round 3
// 176.704 us; speedup vs baseline: 1.4005x; 1.1521x over previous
//
#include <hip/hip_runtime.h>

// PointGatedBlock: SE3 point conv + gated nonlinearity. fp32 in/out.
// R12 = R11 at spill-free occupancy. R11 showed natural footprint ~99 unified
// VGPRs -> cap 84 (6 waves/EU) spills ~15 regs/thread AND still doesn't fit a
// 3rd block/CU. So: __launch_bounds__(512,4) (budget 128, no spill, 2 blk/CU,
// same occupancy as the 63us R9) and test the L2-direct-feat structure clean.
// GEMM1 B-fragments read straight from the L2-resident bf16 feat buffer
// (0.85 MB): lane l15 = row, 16B chunks, 2 kk-steps cover an aligned 128B/row
// segment. No feat LDS staging -> LDS 32.8KB, ~half the LDS pipe traffic of
// R9. WRITE_PHI merged into COMPUTE_PHI (no pk[8] array, -8 regs).
// Single-barrier fused-phase m-loop: barrier -> phi(s+1) compute+write to
// other buffer -> LOAD_DM(s+2) -> GEMM1(s). Pre-kernel converts W+feat to
// bf16 in d_ws. grid 512 = (b, 8-n); block 512; XOR-swizzled phi rows.

typedef __attribute__((ext_vector_type(4))) float f32x4;
typedef __attribute__((ext_vector_type(8))) short s16x8;

#define DI 104
#define DO 144
#define TTST 1688          // Tt row stride (elems)
#define YST 9

#define W_ELEMS 239616     // 16*144*104
#define F_ELEMS 425984     // 4*104*1024

// LDS byte offsets (phi rows: 64 elems = 128 B, XOR-swizzled blocks)
#define OFF_PHI0 0
#define OFF_PHI1 16384                  // 128*64*2
#define OFF_Y 27008                     // behind Tt (8*1688*2) in phi region
#define SMEM_TOTAL 32768                // 32.8KB

__device__ __forceinline__ float fexp2(float x) {
#if __has_builtin(__builtin_amdgcn_exp2f)
    return __builtin_amdgcn_exp2f(x);
#else
    return exp2f(x);
#endif
}
__device__ __forceinline__ float flog2(float x) {
#if __has_builtin(__builtin_amdgcn_logf)
    return __builtin_amdgcn_logf(x);
#else
    return log2f(x);
#endif
}
__device__ __forceinline__ float fsqrt_(float x) {
#if __has_builtin(__builtin_amdgcn_sqrtf)
    return __builtin_amdgcn_sqrtf(x);
#else
    return sqrtf(x);
#endif
}
__device__ __forceinline__ float frcp_(float x) {
#if __has_builtin(__builtin_amdgcn_rcpf)
    return __builtin_amdgcn_rcpf(x);
#else
    return 1.0f / x;
#endif
}
__device__ __forceinline__ unsigned int pkbf(float lo, float hi) {
    unsigned int a = __builtin_bit_cast(unsigned int, lo) + 0x8000u;
    unsigned int b = __builtin_bit_cast(unsigned int, hi) + 0x8000u;
    return __builtin_amdgcn_perm(b, a, 0x07060302u);
}
__device__ __forceinline__ unsigned short f2b(float f) {
    return (unsigned short)((__builtin_bit_cast(unsigned int, f) + 0x8000u) >> 16);
}

// ---- pre-kernel: fp32 -> bf16 for W (ws[0..W_ELEMS)) and feat (ws[W_ELEMS..)) ----
__global__ __launch_bounds__(256, 8)
void cvt_kernel(const float* __restrict__ feat_g, const float* __restrict__ W_g,
                unsigned short* __restrict__ ws)
{
    int gid = blockIdx.x * 256 + threadIdx.x;           // 8 elems per thread
    const float* src;
    unsigned short* dst;
    if (gid < W_ELEMS/8) {
        src = W_g + gid*8;  dst = ws + gid*8;
    } else {
        int g2 = gid - W_ELEMS/8;
        src = feat_g + g2*8; dst = ws + W_ELEMS + g2*8;
    }
    f32x4 a = *(const f32x4*)src;
    f32x4 b = *(const f32x4*)(src + 4);
    unsigned int o[4] = { pkbf(a[0],a[1]), pkbf(a[2],a[3]), pkbf(b[0],b[1]), pkbf(b[2],b[3]) };
    *(f32x4*)dst = *(f32x4*)o;
}

// load-tile macro: diff/mask regs for this thread's (n-row, 2 m cols) at m-base M0
#define LOAD_DM(M0)                                                    \
    do {                                                               \
        const float* dp_ = diff_g + (dmrow + (M0) + pml)*3;            \
        dx0 = dp_[0]; dy0 = dp_[1]; dz0 = dp_[2];                      \
        dx1 = dp_[3]; dy1 = dp_[4]; dz1 = dp_[5];                      \
        const float* mp_ = mask_g + dmrow + (M0) + pml;                \
        mk0 = mp_[0]; mk1 = mp_[1];                                    \
    } while (0)

// phi from current dx../mk regs; each packed bf16x2 written to LDS as computed
// (no pk[] array -> 8 fewer live VGPRs than the R9/R11 two-step form)
#define COMPUTE_WRITE_PHI(BUF)                                         \
    do {                                                               \
        unsigned short* pw_ = (BUF) + phirow;                          \
        float r0_ = fsqrt_(fmaf(dx0,dx0, fmaf(dy0,dy0, fmaf(dz0,dz0, 1e-12f)))); \
        float r1_ = fsqrt_(fmaf(dx1,dx1, fmaf(dy1,dy1, fmaf(dz1,dz1, 1e-12f)))); \
        float t0_ = r0_ - K0OFF, t1_ = r1_ - K0OFF;                    \
        float E0_ = fmaf(CEXP*t0_, t0_, flog2(mk0));                   \
        float E1_ = fmaf(CEXP*t1_, t1_, flog2(mk1));                   \
        float s0_ = fmaf(A1, r0_, S0B);                                \
        float s1_ = fmaf(A1, r1_, S0B);                                \
        _Pragma("unroll")                                              \
        for (int j_ = 0; j_ < 8; ++j_) {                               \
            *(unsigned int*)(pw_ + j_*64 + ((pblk ^ j_) << 3)) =       \
                pkbf(fexp2(E0_), fexp2(E1_));                          \
            E0_ += s0_; s0_ += V2;                                     \
            E1_ += s1_; s1_ += V2;                                     \
        }                                                              \
    } while (0)

// GEMM1: A (phi) from LDS (swizzled), B (feat) from L2-resident global bf16.
// MB = m element base of this tile (s*64). boff[cc] = per-lane feat elem offset
// (b*DI*1024 + i_row*1024 + q*8); kk adds 32 elems, folds into the load imm.
// coltile 6 rows >= DI guarded by exec (l15<8) -> no OOB access, zeros fed in.
#define GEMM1(PBUF, MB)                                                \
    do {                                                               \
        _Pragma("unroll")                                              \
        for (int kk_ = 0; kk_ < 2; ++kk_) {                            \
            const int mo_ = ((kk_*4 + q) ^ sw) << 3;                   \
            s16x8 a0_ = *(const s16x8*)((PBUF) + ((2*wr    )*16 + l15)*64 + mo_); \
            s16x8 a1_ = *(const s16x8*)((PBUF) + ((2*wr + 1)*16 + l15)*64 + mo_); \
            _Pragma("unroll")                                          \
            for (int cc_ = 0; cc_ < 4; ++cc_) {                        \
                if (ct0 + cc_ < 7) {                                   \
                    s16x8 bf_;                                         \
                    if (ct0 + cc_ == 6) {                              \
                        bf_ = (s16x8){0,0,0,0,0,0,0,0};                \
                        if (l15 < 8)                                   \
                            bf_ = *(const s16x8*)(featbf + boff[cc_] + (MB) + kk_*32); \
                    } else {                                           \
                        bf_ = *(const s16x8*)(featbf + boff[cc_] + (MB) + kk_*32); \
                    }                                                  \
                    acc[0][cc_] = __builtin_amdgcn_mfma_f32_16x16x32_bf16(a0_, bf_, acc[0][cc_], 0, 0, 0); \
                    acc[1][cc_] = __builtin_amdgcn_mfma_f32_16x16x32_bf16(a1_, bf_, acc[1][cc_], 0, 0, 0); \
                }                                                      \
            }                                                          \
        }                                                              \
    } while (0)

__global__ __launch_bounds__(512, 4)
void pgb_kernel(const unsigned short* __restrict__ ws,   // Wbf | featbf
                const float* __restrict__ diff_g,
                const float* __restrict__ mask_g,
                float* __restrict__ out_g)
{
    const unsigned short* Wbf    = ws;
    const unsigned short* featbf = ws + W_ELEMS;

    __shared__ __align__(16) unsigned char smem[SMEM_TOTAL];
    unsigned short* Tt   = (unsigned short*)smem;        // aliases phi bufs (post-barrier)
    float*          ylds = (float*)(smem + OFF_Y);       // behind Tt, still in phi region
    unsigned short* phi0b  = (unsigned short*)(smem + OFF_PHI0);
    unsigned short* phi1b  = (unsigned short*)(smem + OFF_PHI1);

    const int t    = threadIdx.x;
    const int b    = blockIdx.x >> 7;
    const int n0   = (blockIdx.x & 127) << 3;
    const int wave = t >> 6;
    const int lane = t & 63;
    const int l15  = lane & 15;
    const int q    = lane >> 4;
    const int wr   = wave >> 1;          // rowgroup: rowtiles 2wr, 2wr+1 (n_local)
    const int ct0  = (wave & 1) << 2;    // colgroup: coltiles ct0..ct0+3 (skip 7)
    const int sw   = l15 & 7;            // read-side swizzle key (row&7)

    f32x4 acc[2][4];
#pragma unroll
    for (int rr = 0; rr < 2; ++rr)
#pragma unroll
        for (int cc = 0; cc < 4; ++cc)
            acc[rr][cc] = (f32x4){0.f, 0.f, 0.f, 0.f};

    // phi thread mapping: 8 n x 2 k-halves x 32 m-pairs
    const int pn   = t >> 6;             // n-row 0..7 (== wave)
    const int kh   = (t >> 5) & 1;       // k-half: k0 = 8*kh
    const int pml  = (t & 31) << 1;      // m pair (even), 0..62
    const int pblk = (t & 31) >> 2;      // m block 0..7 (write-side swizzle base)
    const int phirow = (pn*16 + kh*8)*64 + (pml & 7);   // phi write base (elems)
    const float CEXP = -23.083120654223414f;   // -GAMMA * log2(e)
    const float A1   = 6.155498841126244f;     // -2*CEXP*DL
    const float V2   = -0.8207331788168325f;   // 2*CEXP*DL^2
    const float K0OFF = kh ? 1.0666666666666667f : 0.f;
    const float S0B   = kh ? -6.976232019943076f : -0.41036658940841624f;
    const size_t dmrow = (size_t)((b << 10) + n0 + pn) << 10;

    // GEMM1 B-operand global offsets (elems): row i = (ct0+cc)*16 + l15.
    // Lanes of coltile 6 with i >= DI never load (l15<8 guard in GEMM1).
    unsigned int boff[4];
#pragma unroll
    for (int cc = 0; cc < 4; ++cc)
        boff[cc] = (unsigned int)(b * DI * 1024)
                 + (unsigned int)(((ct0 + cc) * 16 + l15) * 1024)
                 + (unsigned int)(q << 3);

    float dx0, dy0, dz0, dx1, dy1, dz1, mk0, mk1;

    // ---- prologue: phi tile 0 -> buf0; then preload tile 1 diff/mask regs ----
    LOAD_DM(0);
    COMPUTE_WRITE_PHI(phi0b);
    LOAD_DM(64);

    // ---- main loop: iter s reads buf(s&1), writes phi tile s+1 -> buf(~s&1) ----
    for (int s = 0; s < 15; ++s) {
        unsigned short* rp = (s & 1) ? phi1b : phi0b;
        unsigned short* wp = (s & 1) ? phi0b : phi1b;
        __syncthreads();
        // phi(s+1) from regs loaded last iter, write into the other buffer.
        COMPUTE_WRITE_PHI(wp);
        // reissue diff/mask loads for tile s+2: consumed next iter after the
        // next barrier -> a full region (GEMM1 + next phi) of latency cover.
        {
            const int mnext = (s < 14 ? (s + 2) : 15) * 64;
            LOAD_DM(mnext);
        }
        // GEMM1 on tile s: phi from LDS, feat direct from L2 bf16 buffer —
        // co-scheduled with the exp2 VALU above; phi VALU covers L2 latency.
        GEMM1(rp, s << 6);
    }
    __syncthreads();
    GEMM1(phi1b, 15 << 6);              // tail: tile 15 lives in buf1

    __syncthreads();   // phi bufs free -> Tt may overwrite

    // ---- acc (C: col=l15=i_local, row=q*4+r=k; tiles (n_local, i-tile)) -> Tt[n][k*104+i]
#pragma unroll
    for (int rr = 0; rr < 2; ++rr) {
        int nloc = 2*wr + rr;
#pragma unroll
        for (int cc = 0; cc < 4; ++cc) {
            int i = (ct0+cc)*16 + l15;
            if (ct0 + cc < 7 && i < DI) {
#pragma unroll
                for (int r = 0; r < 4; ++r)
                    Tt[nloc*TTST + (q*4+r)*DI + i] = f2b(acc[rr][cc][r]);
            }
        }
    }
    __syncthreads();

    // ---- GEMM2: y[o,n] = sum_ki Wbf[k,o,i]*Tt[n][ki]; 52 K-steps of 32 ----
    f32x4 y0 = (f32x4){0.f,0.f,0.f,0.f}, y1 = (f32x4){0.f,0.f,0.f,0.f};
    const int o0 = wave*16 + l15;
    const int o1 = 128 + l15;            // o-tile 8, wave 0's second acc
#pragma unroll 4
    for (int s3 = 0; s3 < 52; ++s3) {
        int a = s3*4 + q;                // 8-elem ki block; k=a/13, i=(a%13)*8
        int k = a / 13;
        int i = (a - k*13) << 3;
        s16x8 bf = *(const s16x8*)(Tt + (l15 & 7)*TTST + s3*32 + q*8);
        s16x8 af = *(const s16x8*)(Wbf + (size_t)(k*DO + o0)*DI + i);
        y0 = __builtin_amdgcn_mfma_f32_16x16x32_bf16(af, bf, y0, 0, 0, 0);
        if (wave == 0) {
            s16x8 ag = *(const s16x8*)(Wbf + (size_t)(k*DO + o1)*DI + i);
            y1 = __builtin_amdgcn_mfma_f32_16x16x32_bf16(ag, bf, y1, 0, 0, 0);
        }
    }
    if (l15 < 8) {
#pragma unroll
        for (int r = 0; r < 4; ++r)
            ylds[(wave*16 + q*4 + r)*YST + l15] = y0[r];
        if (wave == 0) {
#pragma unroll
            for (int r = 0; r < 4; ++r)
                ylds[(128 + q*4 + r)*YST + l15] = y1[r];
        }
    }
    __syncthreads();

    // ---- gating epilogue: out[b, o(<120), n0+nn] fp32 ----
    const float L2E = 1.4426950408889634f;
    for (int idx = t; idx < 120*8; idx += 512) {
        int o = idx >> 3, nn = idx & 7;
        float y = ylds[o*YST + nn];
        float v;
        if (o < 32) {
            v = fmaxf(y, 0.f);
        } else if (o < 80) {
            float g = ylds[(120 + (o-32)/3)*YST + nn];
            v = y * frcp_(1.f + fexp2(-g*L2E));
        } else {
            float g = ylds[(136 + (o-80)/5)*YST + nn];
            v = y * frcp_(1.f + fexp2(-g*L2E));
        }
        out_g[((size_t)(b*120 + o) << 10) + n0 + nn] = v;
    }
}

extern "C" void kernel_launch(void* const* d_in, const int* in_sizes, int n_in,
                              void* d_out, int out_size, void* d_ws, size_t ws_size,
                              hipStream_t stream) {
    const float* feat = (const float*)d_in[0];  // [4,104,1024] fp32
    const float* diff = (const float*)d_in[1];  // [4,1024,1024,3] fp32
    const float* mask = (const float*)d_in[2];  // [4,1024,1024] fp32
    const float* W    = (const float*)d_in[3];  // [16,144,104] fp32
    float* out = (float*)d_out;                 // [4,120,1024] fp32
    unsigned short* ws = (unsigned short*)d_ws; // Wbf (479 KB) + featbf (852 KB)
    (void)in_sizes; (void)n_in; (void)out_size; (void)ws_size;
    cvt_kernel<<<dim3((W_ELEMS + F_ELEMS)/8/256), dim3(256), 0, stream>>>(feat, W, ws);
    pgb_kernel<<<dim3(512), dim3(512), 0, stream>>>(ws, diff, mask, out);
}

// Round 5
// 174.717 us; speedup vs baseline: 1.4164x; 1.0114x over previous
//
#include <hip/hip_runtime.h>

// PointGatedBlock: SE3 point conv + gated nonlinearity. fp32 in/out.
// R14 = R13 resubmitted (R13's bench died at container acquisition: no timing
// stages in the result -> kernel never ran; audit found no crash/hang risk).
// Occupancy attack: R9-R12 showed 512 blocks = 2 blocks/CU (grid-bound), ~84
// unified VGPR blocks occupancy, no pipe above 40% -> latency-bound.
// This round: 1024 blocks x 4 n-rows, 4 blocks/CU, <=64 unified VGPR via
// acc[4] (one n-tile per wave) + feat staged by global_load_lds DMA (no fr
// regs, no staging VALU; gp2 derived per-call from gp1, -2 VGPR vs R13).
// LDS 36.9KB: phi single-buf (8KB) + feat double-buf (2x14.3KB, 112 rows incl
// zero pad). 2 barriers/iter: [A] DMA(s+1)->other feat buf || GEMM1(s) from
// LDS; [B] phi(s+1) compute+write || LOAD_DM(s+2). DMA latency covered by
// GEMM1; swizzle done on the per-lane GLOBAL source addr (LDS dest linear).
// phi exp2 count 20->8/thread via exact multiplicative finite differences
// (anchored per 4-k quarter -> no underflow-visible error).

typedef __attribute__((ext_vector_type(4))) float f32x4;
typedef __attribute__((ext_vector_type(8))) short s16x8;

#define DI 104
#define DO 144
#define TTST 1688          // Tt row stride (elems)
#define YST 9

#define W_ELEMS 239616     // 16*144*104
#define F_ELEMS 425984     // 4*104*1024

// LDS layout (m-loop): phi [64 rows][64 m] bf16 + 2 feat bufs [112][64] bf16.
// Epilogue aliases: Tt [4][1688] bf16 at 0, ylds behind it.
#define OFF_PHI   0
#define OFF_FEAT0 8192
#define OFF_FEAT1 22528
#define OFF_Y     13504                 // 4*1688*2 = 13504 (Tt end)
#define SMEM_TOTAL 36864                // -> 4 blocks/CU (147KB of 160KB)

#define AS1 __attribute__((address_space(1)))
#define AS3 __attribute__((address_space(3)))

__device__ __forceinline__ float fexp2(float x) {
#if __has_builtin(__builtin_amdgcn_exp2f)
    return __builtin_amdgcn_exp2f(x);
#else
    return exp2f(x);
#endif
}
__device__ __forceinline__ float flog2(float x) {
#if __has_builtin(__builtin_amdgcn_logf)
    return __builtin_amdgcn_logf(x);
#else
    return log2f(x);
#endif
}
__device__ __forceinline__ float fsqrt_(float x) {
#if __has_builtin(__builtin_amdgcn_sqrtf)
    return __builtin_amdgcn_sqrtf(x);
#else
    return sqrtf(x);
#endif
}
__device__ __forceinline__ float frcp_(float x) {
#if __has_builtin(__builtin_amdgcn_rcpf)
    return __builtin_amdgcn_rcpf(x);
#else
    return 1.0f / x;
#endif
}
__device__ __forceinline__ unsigned int pkbf(float lo, float hi) {
    unsigned int a = __builtin_bit_cast(unsigned int, lo) + 0x8000u;
    unsigned int b = __builtin_bit_cast(unsigned int, hi) + 0x8000u;
    return __builtin_amdgcn_perm(b, a, 0x07060302u);
}
__device__ __forceinline__ unsigned short f2b(float f) {
    return (unsigned short)((__builtin_bit_cast(unsigned int, f) + 0x8000u) >> 16);
}

// ---- pre-kernel: fp32 -> bf16 for W (ws[0..W_ELEMS)) and feat (ws[W_ELEMS..)) ----
__global__ __launch_bounds__(256, 8)
void cvt_kernel(const float* __restrict__ feat_g, const float* __restrict__ W_g,
                unsigned short* __restrict__ ws)
{
    int gid = blockIdx.x * 256 + threadIdx.x;           // 8 elems per thread
    const float* src;
    unsigned short* dst;
    if (gid < W_ELEMS/8) {
        src = W_g + gid*8;  dst = ws + gid*8;
    } else {
        int g2 = gid - W_ELEMS/8;
        src = feat_g + g2*8; dst = ws + W_ELEMS + g2*8;
    }
    f32x4 a = *(const f32x4*)src;
    f32x4 b = *(const f32x4*)(src + 4);
    unsigned int o[4] = { pkbf(a[0],a[1]), pkbf(a[2],a[3]), pkbf(b[0],b[1]), pkbf(b[2],b[3]) };
    *(f32x4*)dst = *(f32x4*)o;
}

// load-tile macro: diff/mask regs for this thread's (n-row, 2 m cols) at m-base M0
#define LOAD_DM(M0)                                                    \
    do {                                                               \
        const float* dp_ = diff_g + (dmrow + (M0) + pml)*3;            \
        dx0 = dp_[0]; dy0 = dp_[1]; dz0 = dp_[2];                      \
        dx1 = dp_[3]; dy1 = dp_[4]; dz1 = dp_[5];                      \
        const float* mp_ = mask_g + dmrow + (M0) + pml;                \
        mk0 = mp_[0]; mk1 = mp_[1];                                    \
    } while (0)

// phi for 4 k's (group kq) x 2 m-cols via exact multiplicative finite diffs:
// exp2(E_{j+1}) = exp2(E_j)*exp2(s_j), exp2(s_{j+1}) = exp2(s_j)*2^V2.
// 8 transcendentals/thread (2 sqrt, 2 log2, 4 exp2) vs 20 in the naive form.
#define COMPUTE_WRITE_PHI()                                            \
    do {                                                               \
        unsigned short* pw_ = phib + phirow;                           \
        float r0_ = fsqrt_(fmaf(dx0,dx0, fmaf(dy0,dy0, fmaf(dz0,dz0, 1e-12f)))); \
        float r1_ = fsqrt_(fmaf(dx1,dx1, fmaf(dy1,dy1, fmaf(dz1,dz1, 1e-12f)))); \
        float t0_ = r0_ - K0OFF, t1_ = r1_ - K0OFF;                    \
        float v0_ = fexp2(fmaf(CEXP*t0_, t0_, flog2(mk0)));            \
        float v1_ = fexp2(fmaf(CEXP*t1_, t1_, flog2(mk1)));            \
        float w0_ = fexp2(fmaf(A1, r0_, S0B));                         \
        float w1_ = fexp2(fmaf(A1, r1_, S0B));                         \
        *(unsigned int*)(pw_ + ((pblk ^ kx) << 3)) = pkbf(v0_, v1_);   \
        _Pragma("unroll")                                              \
        for (int j_ = 1; j_ < 4; ++j_) {                               \
            v0_ *= w0_; w0_ *= U2;                                     \
            v1_ *= w1_; w1_ *= U2;                                     \
            *(unsigned int*)(pw_ + j_*64 + ((pblk ^ (kx + j_)) << 3)) = pkbf(v0_, v1_); \
        }                                                              \
    } while (0)

// async feat staging: 13 chunks of 8 rows x 128B; wave w DMAs chunk w (all)
// and chunk w+8 (waves 0-4; source = gp1 + 64 rows, LDS dest = ch1b + 8KB).
// Global source is pre-swizzled by (lane>>3) so the linear LDS dest ends up
// XOR-swizzled: LDS[row][c] = feat[row][c^(row&7)].
#define DMA_FEAT(DSTOFF)                                               \
    do {                                                               \
        __builtin_amdgcn_global_load_lds((const AS1 void*)gp1,         \
            (AS3 void*)(smem + (DSTOFF) + ch1b), 16, 0, 0);            \
        if (wave < 5) {                                                \
            __builtin_amdgcn_global_load_lds((const AS1 void*)(gp1 + 65536), \
                (AS3 void*)(smem + (DSTOFF) + ch1b + 8192), 16, 0, 0); \
        }                                                              \
        gp1 += 64;                                                     \
    } while (0)

// GEMM1: per wave one n-tile (nloc), 4 coltiles (ct0..ct0+3, skip 7).
// A (phi) + B (feat) both from LDS, XOR-swizzled reads (key = l15&7).
// Coltile 6 rows 104-111 are zeroed LDS pad -> no guards needed.
#define GEMM1(FBUF)                                                    \
    do {                                                               \
        _Pragma("unroll")                                              \
        for (int kk_ = 0; kk_ < 2; ++kk_) {                            \
            const int mo_ = ((kk_*4 + q) ^ sw) << 3;                   \
            s16x8 a0_ = *(const s16x8*)(phib + (nloc*16 + l15)*64 + mo_); \
            _Pragma("unroll")                                          \
            for (int cc_ = 0; cc_ < 4; ++cc_) {                        \
                if (ct0 + cc_ < 7) {                                   \
                    s16x8 bf_ = *(const s16x8*)((FBUF) + ((ct0+cc_)*16 + l15)*64 + mo_); \
                    acc[cc_] = __builtin_amdgcn_mfma_f32_16x16x32_bf16(a0_, bf_, acc[cc_], 0, 0, 0); \
                }                                                      \
            }                                                          \
        }                                                              \
    } while (0)

__global__ __launch_bounds__(512, 8)
void pgb_kernel(const unsigned short* __restrict__ ws,   // Wbf | featbf
                const float* __restrict__ diff_g,
                const float* __restrict__ mask_g,
                float* __restrict__ out_g)
{
    const unsigned short* Wbf    = ws;
    const unsigned short* featbf = ws + W_ELEMS;

    __shared__ __align__(16) unsigned char smem[SMEM_TOTAL];
    unsigned short* Tt   = (unsigned short*)smem;        // epilogue alias
    float*          ylds = (float*)(smem + OFF_Y);
    unsigned short* phib = (unsigned short*)(smem + OFF_PHI);
    unsigned short* fb0  = (unsigned short*)(smem + OFF_FEAT0);
    unsigned short* fb1  = (unsigned short*)(smem + OFF_FEAT1);

    const int t    = threadIdx.x;
    const int b    = blockIdx.x >> 8;
    const int n0   = (blockIdx.x & 255) << 2;
    const int wave = t >> 6;
    const int lane = t & 63;
    const int l15  = lane & 15;
    const int q    = lane >> 4;
    const int nloc = wave >> 1;          // n-row tile (0..3)
    const int ct0  = (wave & 1) << 2;    // colgroup: coltiles ct0..ct0+3 (skip 7)
    const int sw   = l15 & 7;            // read-side swizzle key (row&7)

    // zero feat pad rows 104..111 (1KB per buffer); DMA never touches them
    if (t < 256) ((unsigned int*)(smem + OFF_FEAT0 + 13312))[t] = 0u;
    else         ((unsigned int*)(smem + OFF_FEAT1 + 13312))[t - 256] = 0u;

    f32x4 acc[4];
#pragma unroll
    for (int cc = 0; cc < 4; ++cc)
        acc[cc] = (f32x4){0.f, 0.f, 0.f, 0.f};

    // phi thread mapping: 4 n x 4 k-quarters x 32 m-pairs
    const int pn4  = t >> 7;             // n-row 0..3
    const int kq   = (t >> 5) & 3;       // k-quarter: k0 = 4*kq
    const int pml  = (t & 31) << 1;      // m pair (even), 0..62
    const int pblk = (t & 31) >> 2;      // m block 0..7 (write-side swizzle base)
    const int kx   = (kq & 1) << 2;      // row&7 base for this k-quarter
    const int phirow = (pn4*16 + kq*4)*64 + (pml & 7);
    const float CEXP = -23.083120654223414f;   // -GAMMA * log2(e)
    const float A1   = 6.155498841126244f;     // -2*CEXP*DL
    const float V2   = -0.8207331788168325f;   // 2*CEXP*DL^2
    const float U2   = fexp2(V2);              // 2^V2 (uniform)
    const float K0OFF = 0.5333333333333333f * (float)kq;          // 4*kq*DL
    const float S0B   = fmaf(-3.2829327152673303f, (float)kq,     // CEXP*DL^2*(8kq+1)
                             -0.41036658940841624f);
    const size_t dmrow = (size_t)((b << 10) + n0 + pn4) << 10;

    // DMA source pointer (pre-swizzled): chunk ch covers rows ch*8..ch*8+7;
    // lane: row = ch*8 + (lane>>3), reads feat[row][(lane&7)^(lane>>3)] 16B.
    const size_t fbase = (size_t)b * DI << 10;
    const int r8  = lane >> 3;
    const int c8x = ((lane & 7) ^ r8) << 3;
    const unsigned short* gp1 = featbf + fbase + (size_t)((wave*8 + r8)*1024 + c8x);
    const int ch1b = __builtin_amdgcn_readfirstlane(wave << 10);         // LDS byte base

    float dx0, dy0, dz0, dx1, dy1, dz1, mk0, mk1;

    // ---- prologue: DMA tile 0 -> fb0; dm regs tile 0; barrier; phi(0); dm(1)
    DMA_FEAT(OFF_FEAT0);
    LOAD_DM(0);
    __syncthreads();                    // pads + DMA(0) drained (vmcnt0 at barrier)
    COMPUTE_WRITE_PHI();                // phi tile 0
    LOAD_DM(64);                        // dm regs tile 1

    // ---- main loop: 2 barriers/iter. A: phi(s) visible -> DMA(s+1) || GEMM1(s).
    // B: GEMM1 reads done + DMA drained -> phi(s+1) write || LOAD_DM(s+2).
    for (int s = 0; s < 16; ++s) {
        __syncthreads();                                  // A
        if (s < 15) DMA_FEAT((s & 1) ? OFF_FEAT0 : OFF_FEAT1);  // tile s+1 -> buf (s+1)&1
        GEMM1((s & 1) ? fb1 : fb0);                       // tile s
        __syncthreads();                                  // B
        if (s < 15) {
            COMPUTE_WRITE_PHI();                          // phi tile s+1
            const int mnext = (s < 14 ? (s + 2) : 15) * 64;
            LOAD_DM(mnext);
        }
    }

    // ---- acc (C: col=l15=i_local, row=q*4+r=k) -> Tt[nloc][k*104+i] (bf16)
#pragma unroll
    for (int cc = 0; cc < 4; ++cc) {
        int i = (ct0+cc)*16 + l15;
        if (ct0 + cc < 7 && i < DI) {
#pragma unroll
            for (int r = 0; r < 4; ++r)
                Tt[nloc*TTST + (q*4+r)*DI + i] = f2b(acc[cc][r]);
        }
    }
    __syncthreads();

    // ---- GEMM2: y[o,n] = sum_ki Wbf[k,o,i]*Tt[n][ki]; 52 K-steps of 32 ----
    f32x4 y0 = (f32x4){0.f,0.f,0.f,0.f}, y1 = (f32x4){0.f,0.f,0.f,0.f};
    const int o0 = wave*16 + l15;
    const int o1 = 128 + l15;            // o-tile 8, wave 0's second acc
#pragma unroll 4
    for (int s3 = 0; s3 < 52; ++s3) {
        int a = s3*4 + q;                // 8-elem ki block; k=a/13, i=(a%13)*8
        int k = a / 13;
        int i = (a - k*13) << 3;
        s16x8 bf = *(const s16x8*)(Tt + (l15 & 3)*TTST + s3*32 + q*8);
        s16x8 af = *(const s16x8*)(Wbf + (size_t)(k*DO + o0)*DI + i);
        y0 = __builtin_amdgcn_mfma_f32_16x16x32_bf16(af, bf, y0, 0, 0, 0);
        if (wave == 0) {
            s16x8 ag = *(const s16x8*)(Wbf + (size_t)(k*DO + o1)*DI + i);
            y1 = __builtin_amdgcn_mfma_f32_16x16x32_bf16(ag, bf, y1, 0, 0, 0);
        }
    }
    if (l15 < 4) {
#pragma unroll
        for (int r = 0; r < 4; ++r)
            ylds[(wave*16 + q*4 + r)*YST + l15] = y0[r];
        if (wave == 0) {
#pragma unroll
            for (int r = 0; r < 4; ++r)
                ylds[(128 + q*4 + r)*YST + l15] = y1[r];
        }
    }
    __syncthreads();

    // ---- gating epilogue: out[b, o(<120), n0+nn] fp32; 480 items ----
    const float L2E = 1.4426950408889634f;
    if (t < 480) {
        int o = t >> 2, nn = t & 3;
        float y = ylds[o*YST + nn];
        float v;
        if (o < 32) {
            v = fmaxf(y, 0.f);
        } else if (o < 80) {
            float g = ylds[(120 + (o-32)/3)*YST + nn];
            v = y * frcp_(1.f + fexp2(-g*L2E));
        } else {
            float g = ylds[(136 + (o-80)/5)*YST + nn];
            v = y * frcp_(1.f + fexp2(-g*L2E));
        }
        out_g[((size_t)(b*120 + o) << 10) + n0 + nn] = v;
    }
}

extern "C" void kernel_launch(void* const* d_in, const int* in_sizes, int n_in,
                              void* d_out, int out_size, void* d_ws, size_t ws_size,
                              hipStream_t stream) {
    const float* feat = (const float*)d_in[0];  // [4,104,1024] fp32
    const float* diff = (const float*)d_in[1];  // [4,1024,1024,3] fp32
    const float* mask = (const float*)d_in[2];  // [4,1024,1024] fp32
    const float* W    = (const float*)d_in[3];  // [16,144,104] fp32
    float* out = (float*)d_out;                 // [4,120,1024] fp32
    unsigned short* ws = (unsigned short*)d_ws; // Wbf (479 KB) + featbf (852 KB)
    (void)in_sizes; (void)n_in; (void)out_size; (void)ws_size;
    cvt_kernel<<<dim3((W_ELEMS + F_ELEMS)/8/256), dim3(256), 0, stream>>>(feat, W, ws);
    pgb_kernel<<<dim3(1024), dim3(512), 0, stream>>>(ws, diff, mask, out);
}

// Round 6
// 140.712 us; speedup vs baseline: 1.7587x; 1.2417x over previous
//
#include <hip/hip_runtime.h>

// PointGatedBlock: SE3 point conv + gated nonlinearity. fp32 in/out.
// R15 = R9 (best known, 63us) + phi transcendental reduction proven in R14.
// R14's occupancy attack (4 blk/CU, 76% occ) was SLOWER (99us): n-split
// duplicates per-block feat staging + barriers, and global_load_lds forces
// vmcnt(0) drains at every barrier. Reg-staged R9 structure pipelines better.
// Change vs R9: phi computed via exact multiplicative finite differences --
// v_{j+1} = v_j * w_j, w_{j+1} = w_j * 2^V2 from anchors v0 = exp2(E(k0)),
// w0 = exp2(A1*r + S0B). 8 trans/thread (2 sqrt, 2 log2, 4 exp2) vs 20;
// write-as-computed kills the pk[8] array. Anchor underflow only occurs when
// the whole k-half is < 2^-45 (negligible vs bf16). All else identical to R9:
// single-barrier fused-phase m-loop, feat+phi double-buffered in LDS (reg
// staging, loads issued 1 iter ahead), 67KB LDS, 2 blk/CU, grid 512.

typedef __attribute__((ext_vector_type(4))) float f32x4;
typedef __attribute__((ext_vector_type(8))) short s16x8;

#define DI 104
#define DO 144
#define TTST 1688          // Tt row stride (elems)
#define YST 9

#define W_ELEMS 239616     // 16*144*104
#define F_ELEMS 425984     // 4*104*1024

// LDS byte offsets (phi/feat rows: 64 elems = 128 B, XOR-swizzled blocks)
#define OFF_PHI0 0
#define OFF_PHI1 16384                  // 128*64*2
#define OFF_FEAT0 32768
#define OFF_FEAT1 47104                 // + 112*64*2 = 14336
#define OFF_Y 61440
#define SMEM_TOTAL (61440 + 144*9*4)    // 66624 B -> 2 blocks/CU

__device__ __forceinline__ float fexp2(float x) {
#if __has_builtin(__builtin_amdgcn_exp2f)
    return __builtin_amdgcn_exp2f(x);
#else
    return exp2f(x);
#endif
}
__device__ __forceinline__ float flog2(float x) {
#if __has_builtin(__builtin_amdgcn_logf)
    return __builtin_amdgcn_logf(x);
#else
    return log2f(x);
#endif
}
__device__ __forceinline__ float fsqrt_(float x) {
#if __has_builtin(__builtin_amdgcn_sqrtf)
    return __builtin_amdgcn_sqrtf(x);
#else
    return sqrtf(x);
#endif
}
__device__ __forceinline__ float frcp_(float x) {
#if __has_builtin(__builtin_amdgcn_rcpf)
    return __builtin_amdgcn_rcpf(x);
#else
    return 1.0f / x;
#endif
}
__device__ __forceinline__ unsigned int pkbf(float lo, float hi) {
    unsigned int a = __builtin_bit_cast(unsigned int, lo) + 0x8000u;
    unsigned int b = __builtin_bit_cast(unsigned int, hi) + 0x8000u;
    return __builtin_amdgcn_perm(b, a, 0x07060302u);
}
__device__ __forceinline__ unsigned short f2b(float f) {
    return (unsigned short)((__builtin_bit_cast(unsigned int, f) + 0x8000u) >> 16);
}

// ---- pre-kernel: fp32 -> bf16 for W (ws[0..W_ELEMS)) and feat (ws[W_ELEMS..)) ----
__global__ __launch_bounds__(256, 8)
void cvt_kernel(const float* __restrict__ feat_g, const float* __restrict__ W_g,
                unsigned short* __restrict__ ws)
{
    int gid = blockIdx.x * 256 + threadIdx.x;           // 8 elems per thread
    const float* src;
    unsigned short* dst;
    if (gid < W_ELEMS/8) {
        src = W_g + gid*8;  dst = ws + gid*8;
    } else {
        int g2 = gid - W_ELEMS/8;
        src = feat_g + g2*8; dst = ws + W_ELEMS + g2*8;
    }
    f32x4 a = *(const f32x4*)src;
    f32x4 b = *(const f32x4*)(src + 4);
    unsigned int o[4] = { pkbf(a[0],a[1]), pkbf(a[2],a[3]), pkbf(b[0],b[1]), pkbf(b[2],b[3]) };
    *(f32x4*)dst = *(f32x4*)o;
}

// load-tile macro: diff/mask regs for this thread's (n-row, 2 m cols) at m-base M0
#define LOAD_DM(M0)                                                    \
    do {                                                               \
        const float* dp_ = diff_g + (dmrow + (M0) + pml)*3;            \
        dx0 = dp_[0]; dy0 = dp_[1]; dz0 = dp_[2];                      \
        dx1 = dp_[3]; dy1 = dp_[4]; dz1 = dp_[5];                      \
        const float* mp_ = mask_g + dmrow + (M0) + pml;                \
        mk0 = mp_[0]; mk1 = mp_[1];                                    \
    } while (0)

#define LOAD_FEAT(M0)                                                          \
    do {                                                                       \
        fr0 = *(const s16x8*)(featbf + fbase + ((size_t)fi0 << 10) + (M0) + (fj << 3)); \
        if (t < 320)                                                           \
            fr1 = *(const s16x8*)(featbf + fbase + ((size_t)fi1 << 10) + (M0) + (fj << 3)); \
    } while (0)

// phi for this thread's 8 k's (half kh) x 2 m-cols via exact multiplicative
// finite differences: exp2(E_{j+1}) = exp2(E_j)*exp2(s_j), exp2(s_{j+1}) =
// exp2(s_j)*2^V2. 8 transcendentals (2 sqrt, 2 log2, 4 exp2) vs 20 naive.
// Each packed bf16x2 written to LDS as computed (no pk[] array).
#define COMPUTE_WRITE_PHI(BUF)                                         \
    do {                                                               \
        unsigned short* pw_ = (BUF) + phirow;                          \
        float r0_ = fsqrt_(fmaf(dx0,dx0, fmaf(dy0,dy0, fmaf(dz0,dz0, 1e-12f)))); \
        float r1_ = fsqrt_(fmaf(dx1,dx1, fmaf(dy1,dy1, fmaf(dz1,dz1, 1e-12f)))); \
        float t0_ = r0_ - K0OFF, t1_ = r1_ - K0OFF;                    \
        float v0_ = fexp2(fmaf(CEXP*t0_, t0_, flog2(mk0)));            \
        float v1_ = fexp2(fmaf(CEXP*t1_, t1_, flog2(mk1)));            \
        float w0_ = fexp2(fmaf(A1, r0_, S0B));                         \
        float w1_ = fexp2(fmaf(A1, r1_, S0B));                         \
        *(unsigned int*)(pw_ + (pblk << 3)) = pkbf(v0_, v1_);          \
        _Pragma("unroll")                                              \
        for (int j_ = 1; j_ < 8; ++j_) {                               \
            v0_ *= w0_; w0_ *= U2;                                     \
            v1_ *= w1_; w1_ *= U2;                                     \
            *(unsigned int*)(pw_ + j_*64 + ((pblk ^ j_) << 3)) = pkbf(v0_, v1_); \
        }                                                              \
    } while (0)

#define WRITE_FEAT(BUF)                                                \
    do {                                                               \
        *(s16x8*)((BUF) + fi0*64 + fjs) = fr0;                         \
        if (t < 320) *(s16x8*)((BUF) + fi1*64 + fjs) = fr1;            \
    } while (0)

#define GEMM1(PBUF, FBUF)                                              \
    do {                                                               \
        _Pragma("unroll")                                              \
        for (int kk_ = 0; kk_ < 2; ++kk_) {                            \
            const int mo_ = ((kk_*4 + q) ^ sw) << 3;                   \
            s16x8 a0_ = *(const s16x8*)((PBUF) + ((2*wr    )*16 + l15)*64 + mo_); \
            s16x8 a1_ = *(const s16x8*)((PBUF) + ((2*wr + 1)*16 + l15)*64 + mo_); \
            _Pragma("unroll")                                          \
            for (int cc_ = 0; cc_ < 4; ++cc_) {                        \
                if (ct0 + cc_ < 7) {                                   \
                    s16x8 bf_ = *(const s16x8*)((FBUF) + ((ct0+cc_)*16 + l15)*64 + mo_); \
                    acc[0][cc_] = __builtin_amdgcn_mfma_f32_16x16x32_bf16(a0_, bf_, acc[0][cc_], 0, 0, 0); \
                    acc[1][cc_] = __builtin_amdgcn_mfma_f32_16x16x32_bf16(a1_, bf_, acc[1][cc_], 0, 0, 0); \
                }                                                      \
            }                                                          \
        }                                                              \
    } while (0)

__global__ __launch_bounds__(512, 4)
void pgb_kernel(const unsigned short* __restrict__ ws,   // Wbf | featbf
                const float* __restrict__ diff_g,
                const float* __restrict__ mask_g,
                float* __restrict__ out_g)
{
    const unsigned short* Wbf    = ws;
    const unsigned short* featbf = ws + W_ELEMS;

    __shared__ __align__(16) unsigned char smem[SMEM_TOTAL];
    unsigned short* Tt   = (unsigned short*)smem;        // aliases phi bufs (post-barrier)
    float*          ylds = (float*)(smem + OFF_Y);
    unsigned short* phi0b  = (unsigned short*)(smem + OFF_PHI0);
    unsigned short* phi1b  = (unsigned short*)(smem + OFF_PHI1);
    unsigned short* feat0b = (unsigned short*)(smem + OFF_FEAT0);
    unsigned short* feat1b = (unsigned short*)(smem + OFF_FEAT1);

    const int t    = threadIdx.x;
    const int b    = blockIdx.x >> 7;
    const int n0   = (blockIdx.x & 127) << 3;
    const int wave = t >> 6;
    const int lane = t & 63;
    const int l15  = lane & 15;
    const int q    = lane >> 4;
    const int wr   = wave >> 1;          // rowgroup: rowtiles 2wr, 2wr+1 (n_local)
    const int ct0  = (wave & 1) << 2;    // colgroup: coltiles ct0..ct0+3 (skip 7)
    const int sw   = l15 & 7;            // read-side swizzle key (row&7)

    // zero feat pad rows 104..111 in both buffers
    if (t < 256) {
        ((unsigned int*)(smem + OFF_FEAT0 + DI*128))[t] = 0u;
        ((unsigned int*)(smem + OFF_FEAT1 + DI*128))[t] = 0u;
    }

    f32x4 acc[2][4];
#pragma unroll
    for (int rr = 0; rr < 2; ++rr)
#pragma unroll
        for (int cc = 0; cc < 4; ++cc)
            acc[rr][cc] = (f32x4){0.f, 0.f, 0.f, 0.f};

    // phi thread mapping: 8 n x 2 k-halves x 32 m-pairs
    const int pn   = t >> 6;             // n-row 0..7 (== wave)
    const int kh   = (t >> 5) & 1;       // k-half: k0 = 8*kh
    const int pml  = (t & 31) << 1;      // m pair (even), 0..62
    const int pblk = (t & 31) >> 2;      // m block 0..7 (write-side swizzle base)
    const int phirow = (pn*16 + kh*8)*64 + (pml & 7);   // phi write base (elems)
    const float CEXP = -23.083120654223414f;   // -GAMMA * log2(e)
    const float A1   = 6.155498841126244f;     // -2*CEXP*DL
    const float V2   = -0.8207331788168325f;   // 2*CEXP*DL^2
    const float U2   = fexp2(V2);              // 2^V2 (uniform)
    const float K0OFF = kh ? 1.0666666666666667f : 0.f;
    const float S0B   = kh ? -6.976232019943076f : -0.41036658940841624f;
    const size_t dmrow = (size_t)((b << 10) + n0 + pn) << 10;

    // feat staging mapping
    const int fi0 = t >> 3, fj = t & 7;
    const int fi1 = 64 + (t >> 3);
    const int fjs = (fj ^ (fi0 & 7)) << 3;
    const size_t fbase = (size_t)b * DI << 10;

    float dx0, dy0, dz0, dx1, dy1, dz1, mk0, mk1;
    s16x8 fr0 = {}, fr1 = {};

    // ---- prologue: tile 0 -> buf0; then preload tile 1 regs ----
    LOAD_DM(0);
    LOAD_FEAT(0);
    COMPUTE_WRITE_PHI(phi0b);
    WRITE_FEAT(feat0b);
    LOAD_DM(64);
    LOAD_FEAT(64);

    // ---- main loop: iter s reads buf(s&1), writes tile s+1 -> buf(~s&1) ----
    for (int s = 0; s < 15; ++s) {
        unsigned short* rp = (s & 1) ? phi1b  : phi0b;
        unsigned short* rf = (s & 1) ? feat1b : feat0b;
        unsigned short* wp = (s & 1) ? phi0b  : phi1b;
        unsigned short* wf = (s & 1) ? feat0b : feat1b;
        __syncthreads();
        // phi(s+1) from dm regs loaded last iter, then stage feat tile s+1
        // into the other buffer WHILE fr0/fr1 still hold tile s+1.
        COMPUTE_WRITE_PHI(wp);
        WRITE_FEAT(wf);
        // NOW reissue loads for tile s+2: consumed next iter after the next
        // barrier -> a full region (GEMM1 + next phi) of latency cover.
        {
            const int mnext = (s < 14 ? (s + 2) : 15) * 64;
            LOAD_DM(mnext);
            LOAD_FEAT(mnext);
        }
        // GEMM1 on tile s (LDS) — co-scheduled with the phi VALU above
        GEMM1(rp, rf);
    }
    __syncthreads();
    GEMM1(phi1b, feat1b);               // tail: tile 15 lives in buf1

    __syncthreads();   // phi bufs free -> Tt may overwrite

    // ---- acc (C: col=l15=i_local, row=q*4+r=k; tiles (n_local, i-tile)) -> Tt[n][k*104+i]
#pragma unroll
    for (int rr = 0; rr < 2; ++rr) {
        int nloc = 2*wr + rr;
#pragma unroll
        for (int cc = 0; cc < 4; ++cc) {
            int i = (ct0+cc)*16 + l15;
            if (ct0 + cc < 7 && i < DI) {
#pragma unroll
                for (int r = 0; r < 4; ++r)
                    Tt[nloc*TTST + (q*4+r)*DI + i] = f2b(acc[rr][cc][r]);
            }
        }
    }
    __syncthreads();

    // ---- GEMM2: y[o,n] = sum_ki Wbf[k,o,i]*Tt[n][ki]; 52 K-steps of 32 ----
    f32x4 y0 = (f32x4){0.f,0.f,0.f,0.f}, y1 = (f32x4){0.f,0.f,0.f,0.f};
    const int o0 = wave*16 + l15;
    const int o1 = 128 + l15;            // o-tile 8, wave 0's second acc
#pragma unroll 4
    for (int s3 = 0; s3 < 52; ++s3) {
        int a = s3*4 + q;                // 8-elem ki block; k=a/13, i=(a%13)*8
        int k = a / 13;
        int i = (a - k*13) << 3;
        s16x8 bf = *(const s16x8*)(Tt + (l15 & 7)*TTST + s3*32 + q*8);
        s16x8 af = *(const s16x8*)(Wbf + (size_t)(k*DO + o0)*DI + i);
        y0 = __builtin_amdgcn_mfma_f32_16x16x32_bf16(af, bf, y0, 0, 0, 0);
        if (wave == 0) {
            s16x8 ag = *(const s16x8*)(Wbf + (size_t)(k*DO + o1)*DI + i);
            y1 = __builtin_amdgcn_mfma_f32_16x16x32_bf16(ag, bf, y1, 0, 0, 0);
        }
    }
    if (l15 < 8) {
#pragma unroll
        for (int r = 0; r < 4; ++r)
            ylds[(wave*16 + q*4 + r)*YST + l15] = y0[r];
        if (wave == 0) {
#pragma unroll
            for (int r = 0; r < 4; ++r)
                ylds[(128 + q*4 + r)*YST + l15] = y1[r];
        }
    }
    __syncthreads();

    // ---- gating epilogue: out[b, o(<120), n0+nn] fp32 ----
    const float L2E = 1.4426950408889634f;
    for (int idx = t; idx < 120*8; idx += 512) {
        int o = idx >> 3, nn = idx & 7;
        float y = ylds[o*YST + nn];
        float v;
        if (o < 32) {
            v = fmaxf(y, 0.f);
        } else if (o < 80) {
            float g = ylds[(120 + (o-32)/3)*YST + nn];
            v = y * frcp_(1.f + fexp2(-g*L2E));
        } else {
            float g = ylds[(136 + (o-80)/5)*YST + nn];
            v = y * frcp_(1.f + fexp2(-g*L2E));
        }
        out_g[((size_t)(b*120 + o) << 10) + n0 + nn] = v;
    }
}

extern "C" void kernel_launch(void* const* d_in, const int* in_sizes, int n_in,
                              void* d_out, int out_size, void* d_ws, size_t ws_size,
                              hipStream_t stream) {
    const float* feat = (const float*)d_in[0];  // [4,104,1024] fp32
    const float* diff = (const float*)d_in[1];  // [4,1024,1024,3] fp32
    const float* mask = (const float*)d_in[2];  // [4,1024,1024] fp32
    const float* W    = (const float*)d_in[3];  // [16,144,104] fp32
    float* out = (float*)d_out;                 // [4,120,1024] fp32
    unsigned short* ws = (unsigned short*)d_ws; // Wbf (479 KB) + featbf (852 KB)
    (void)in_sizes; (void)n_in; (void)out_size; (void)ws_size;
    cvt_kernel<<<dim3((W_ELEMS + F_ELEMS)/8/256), dim3(256), 0, stream>>>(feat, W, ws);
    pgb_kernel<<<dim3(512), dim3(512), 0, stream>>>(ws, diff, mask, out);
}